// Round 3
// baseline (165.605 us; speedup 1.0000x reference)
//
#include <hip/hip_runtime.h>
#include <hip/hip_bf16.h>

// Problem dims (fixed by reference):
//   N=2048 nodes, E=64 (node emb), H=64 (hidden), B=32, T=48, C=32
//   gate[n] = sigmoid( relu( concat(u[n],d[n]) @ W1 + b1 ) @ W2 + b2 )
//   out[b,t,n,c] = hist[b,t,n,c] * gate[n]
//
// Total elements: 32*48*2048*32 = 100,663,296 f32  (= 25,165,824 float4)
// Multiply traffic: 402.7 MB read + 402.7 MB write -> roofline ~128 us @6.3TB/s

#define N_NODES 2048
#define E_DIM   64
#define H_DIM   64

// mul geometry — all exact, no tail:
#define TOTAL4      25165824L            // out_size / 4
#define MUL_BLOCK   256
#define MUL_CHUNKS  8                    // float4s per thread
#define MUL_THREADS (TOTAL4 / MUL_CHUNKS)          // 3,145,728
#define MUL_GRID    ((int)(MUL_THREADS / MUL_BLOCK)) // 12,288
#define MUL_STRIDE  MUL_THREADS          // multiple of 8*N_NODES=16384 (x192)

typedef float f32x4 __attribute__((ext_vector_type(4)));

// One wave (64 threads) per node. Thread h computes hidden[h], then a
// 64-lane shuffle reduction produces the H->1 dot product.
__global__ void gate_kernel(const float* __restrict__ u,
                            const float* __restrict__ d,
                            const float* __restrict__ W1,   // [128,64] row-major
                            const float* __restrict__ b1,   // [64]
                            const float* __restrict__ W2,   // [64]
                            const float* __restrict__ b2,   // [1]
                            float* __restrict__ gate) {     // [N]
    const int n = blockIdx.x;
    const int h = threadIdx.x;  // 0..63

    __shared__ float feat[2 * E_DIM];
    feat[h]          = u[n * E_DIM + h];
    feat[h + E_DIM]  = d[n * E_DIM + h];
    __syncthreads();

    float acc = b1[h];
#pragma unroll
    for (int k = 0; k < 2 * E_DIM; ++k) {
        acc = fmaf(feat[k], W1[k * H_DIM + h], acc);  // coalesced over h
    }
    float hid = fmaxf(acc, 0.0f);
    float p = hid * W2[h];

#pragma unroll
    for (int off = 32; off > 0; off >>= 1)
        p += __shfl_down(p, off);

    if (h == 0) {
        float x = p + b2[0];
        gate[n] = 1.0f / (1.0f + expf(-x));
    }
}

// Streaming broadcast multiply, exact cover, no predicates.
// Each thread handles MUL_CHUNKS float4s at stride MUL_STRIDE (a multiple of
// 8*N_NODES), so every chunk shares the SAME node -> one gate load/thread.
// 8 independent non-temporal loads in flight per lane (128 B) to cover HBM
// latency; NT avoids polluting L2 with an 805 MB zero-reuse stream.
__global__ __launch_bounds__(MUL_BLOCK) void mul_kernel(
        const f32x4* __restrict__ hist4,
        const float* __restrict__ gate,
        f32x4* __restrict__ out4) {
    const long base = (long)blockIdx.x * MUL_BLOCK + threadIdx.x;

    // gate index is identical for all chunks; L2-hot (8 KB table)
    const float g = gate[(int)((base >> 3) & (N_NODES - 1))];

    f32x4 v[MUL_CHUNKS];
#pragma unroll
    for (int k = 0; k < MUL_CHUNKS; ++k)
        v[k] = __builtin_nontemporal_load(hist4 + base + (long)k * MUL_STRIDE);

#pragma unroll
    for (int k = 0; k < MUL_CHUNKS; ++k)
        __builtin_nontemporal_store(v[k] * g, out4 + base + (long)k * MUL_STRIDE);
}

extern "C" void kernel_launch(void* const* d_in, const int* in_sizes, int n_in,
                              void* d_out, int out_size, void* d_ws, size_t ws_size,
                              hipStream_t stream) {
    const float* u    = (const float*)d_in[0];  // [N,E]
    const float* dd   = (const float*)d_in[1];  // [N,E]
    const float* hist = (const float*)d_in[2];  // [B,T,N,C]
    const float* W1   = (const float*)d_in[3];  // [2E,H]
    const float* b1   = (const float*)d_in[4];  // [H]
    const float* W2   = (const float*)d_in[5];  // [H,1]
    const float* b2   = (const float*)d_in[6];  // [1]
    float* out  = (float*)d_out;
    float* gate = (float*)d_ws;                 // N floats = 8 KB scratch

    // 1) per-node gate: 2048 blocks x 1 wave (~3 us)
    gate_kernel<<<N_NODES, 64, 0, stream>>>(u, dd, W1, b1, W2, b2, gate);

    // 2) broadcast multiply: exact-cover grid, 8 float4s/thread
    mul_kernel<<<MUL_GRID, MUL_BLOCK, 0, stream>>>((const f32x4*)hist, gate,
                                                   (f32x4*)out);
}

// Round 4
// 139.528 us; speedup vs baseline: 1.1869x; 1.1869x over previous
//
#include <hip/hip_runtime.h>
#include <hip/hip_bf16.h>

// Problem dims (fixed by reference):
//   N=2048 nodes, E=64 (node emb), H=64 (hidden), B=32, T=48, C=32
//   gate[n] = sigmoid( relu( concat(u[n],d[n]) @ W1 + b1 ) @ W2 + b2 )
//   out[b,t,n,c] = hist[b,t,n,c] * gate[n]
//
// Total: 100,663,296 f32 = 25,165,824 float4 = 1536 panels of 16384 float4.
// Multiply traffic: 402.7 MB read + 402.7 MB write -> roofline ~128 us @6.3TB/s

#define N_NODES 2048
#define E_DIM   64
#define H_DIM   64

#define MUL_BLOCK   256
#define MUL_CHUNKS  4
#define PANEL4      16384L               // float4s per panel = 8*N_NODES (x1)
// threads = 25,165,824 / 4 = 6,291,456 = 24576 blocks x 256

typedef float f32x4 __attribute__((ext_vector_type(4)));

// One wave (64 threads) per node. Thread h computes hidden[h], then a
// 64-lane shuffle reduction produces the H->1 dot product.
__global__ void gate_kernel(const float* __restrict__ u,
                            const float* __restrict__ d,
                            const float* __restrict__ W1,   // [128,64] row-major
                            const float* __restrict__ b1,   // [64]
                            const float* __restrict__ W2,   // [64]
                            const float* __restrict__ b2,   // [1]
                            float* __restrict__ gate) {     // [N]
    const int n = blockIdx.x;
    const int h = threadIdx.x;  // 0..63

    __shared__ float feat[2 * E_DIM];
    feat[h]          = u[n * E_DIM + h];
    feat[h + E_DIM]  = d[n * E_DIM + h];
    __syncthreads();

    float acc = b1[h];
#pragma unroll
    for (int k = 0; k < 2 * E_DIM; ++k) {
        acc = fmaf(feat[k], W1[k * H_DIM + h], acc);  // coalesced over h
    }
    float hid = fmaxf(acc, 0.0f);
    float p = hid * W2[h];

#pragma unroll
    for (int off = 32; off > 0; off >>= 1)
        p += __shfl_down(p, off);

    if (h == 0) {
        float x = p + b2[0];
        gate[n] = 1.0f / (1.0f + expf(-x));
    }
}

// Streaming broadcast multiply, exact cover, no predicates.
// Thread t: panel-group pg = t>>14, in-panel offset o = t&16383.
// Chunks at panels 4*pg+k, k=0..3 -> i4 = pg*4*PANEL4 + k*PANEL4 + o.
// Each thread's 4 accesses span only 1 MB (vs 288 MB before) -> good DRAM
// page locality. Panel stride is a multiple of 8*N_NODES, so the node index
// (o>>3) is identical for all chunks -> ONE gate load per thread.
// NT load/store: 805 MB zero-reuse stream, skip L2 pollution.
__global__ __launch_bounds__(MUL_BLOCK) void mul_kernel(
        const f32x4* __restrict__ hist4,
        const float* __restrict__ gate,
        f32x4* __restrict__ out4) {
    const long t  = (long)blockIdx.x * MUL_BLOCK + threadIdx.x;
    const long o  = t & (PANEL4 - 1);
    const long pg = t >> 14;
    const long base = pg * (MUL_CHUNKS * PANEL4) + o;

    const float g = gate[(int)(o >> 3)];  // o < 16384 -> n = o>>3 in [0,2048)

    f32x4 v[MUL_CHUNKS];
#pragma unroll
    for (int k = 0; k < MUL_CHUNKS; ++k)
        v[k] = __builtin_nontemporal_load(hist4 + base + (long)k * PANEL4);

#pragma unroll
    for (int k = 0; k < MUL_CHUNKS; ++k)
        __builtin_nontemporal_store(v[k] * g, out4 + base + (long)k * PANEL4);
}

extern "C" void kernel_launch(void* const* d_in, const int* in_sizes, int n_in,
                              void* d_out, int out_size, void* d_ws, size_t ws_size,
                              hipStream_t stream) {
    const float* u    = (const float*)d_in[0];  // [N,E]
    const float* dd   = (const float*)d_in[1];  // [N,E]
    const float* hist = (const float*)d_in[2];  // [B,T,N,C]
    const float* W1   = (const float*)d_in[3];  // [2E,H]
    const float* b1   = (const float*)d_in[4];  // [H]
    const float* W2   = (const float*)d_in[5];  // [H,1]
    const float* b2   = (const float*)d_in[6];  // [1]
    float* out  = (float*)d_out;
    float* gate = (float*)d_ws;                 // N floats = 8 KB scratch

    // 1) per-node gate: 2048 blocks x 1 wave (~3 us)
    gate_kernel<<<N_NODES, 64, 0, stream>>>(u, dd, W1, b1, W2, b2, gate);

    // 2) broadcast multiply: exact-cover grid, 4 float4s/thread
    const int blocks = 24576;  // 6,291,456 threads x 4 float4 = 25,165,824
    mul_kernel<<<blocks, MUL_BLOCK, 0, stream>>>((const f32x4*)hist, gate,
                                                 (f32x4*)out);
}